// Round 8
// baseline (946.030 us; speedup 1.0000x reference)
//
#include <hip/hip_runtime.h>
#include <math.h>

// No automatic FMA contraction anywhere: numpy-emulation arithmetic
// (square-then-add, sub-then-add) must round exactly like the reference.
// Explicit fmaf() stays fused regardless.
#pragma clang fp contract(off)

#define N_ROWS 32768
#define DIM    256
#define K_EMB  8192
#define BCAP   4096

typedef float  f32x4  __attribute__((ext_vector_type(4)));
typedef short  bf16x8 __attribute__((ext_vector_type(8)));

__device__ __forceinline__ unsigned bf_rne(float f) {
  unsigned u = __float_as_uint(f);
  return (u + 0x7fffu + ((u >> 16) & 1u)) >> 16;   // RNE f32->bf16 (no NaN in data)
}
__device__ __forceinline__ unsigned pack2(float lo, float hi) {
  return bf_rne(lo) | (bf_rne(hi) << 16);
}

// ---------------------------------------------------------------------------
// numpy pairwise_sum emulation (exact order): R2..R7 proven, absmax 0.0.
// ---------------------------------------------------------------------------
__device__ __forceinline__ float np_pw128_sumsq(const float* __restrict__ a) {
  float4 v0 = *(const float4*)(a);
  float4 v1 = *(const float4*)(a + 4);
  float r0 = v0.x*v0.x, r1 = v0.y*v0.y, r2 = v0.z*v0.z, r3 = v0.w*v0.w;
  float r4 = v1.x*v1.x, r5 = v1.y*v1.y, r6 = v1.z*v1.z, r7 = v1.w*v1.w;
  for (int i = 8; i < 128; i += 8) {
    float4 w0 = *(const float4*)(a + i);
    float4 w1 = *(const float4*)(a + i + 4);
    r0 += w0.x*w0.x; r1 += w0.y*w0.y; r2 += w0.z*w0.z; r3 += w0.w*w0.w;
    r4 += w1.x*w1.x; r5 += w1.y*w1.y; r6 += w1.z*w1.z; r7 += w1.w*w1.w;
  }
  return ((r0+r1)+(r2+r3))+((r4+r5)+(r6+r7));
}

__global__ __launch_bounds__(256) void vq_sumsq(const float* __restrict__ src,
                                                float* __restrict__ dst, int nrows) {
  int gid  = blockIdx.x * 256 + threadIdx.x;
  int row  = gid >> 1, half = gid & 1;
  if (row >= nrows) return;
  float s = np_pw128_sumsq(src + (size_t)row * DIM + half * 128);
  float o = __shfl_xor(s, 1);
  if (half == 0) dst[row] = s + o;     // fl(s0 + s1), numpy order
}

// init small arrays (ws poisoned 0xAA by harness) — R6-proven
__global__ __launch_bounds__(256) void vq_init(unsigned* __restrict__ hist,
                                               unsigned* __restrict__ bcnt,
                                               unsigned* __restrict__ ovf,
                                               unsigned long long* __restrict__ best) {
  int i = blockIdx.x * 256 + threadIdx.x;      // grid 128*256 = 32768
  ovf[i]  = 0u;
  best[i] = ~0ull;
  if (i < K_EMB) hist[i] = 0u;
  if (i < 128)   bcnt[i] = 0u;
}

// E f32 -> bf16 in MFMA-fragment-tile order (R6/R7-proven):
//   tile t = cfg*8 + ks; lane l: code = cfg*16 + (l&15), k0 = (ks*4+(l>>4))*8.
// A 128-code chunk = 64 consecutive tiles = 64 KB contiguous (linear LDS copy).
__global__ __launch_bounds__(256) void vq_cvt_frag(const float* __restrict__ E,
                                                   uint4* __restrict__ Eb) {
  int t = blockIdx.x * 256 + threadIdx.x;      // 0..262143 (tile*64 + lane)
  int tile = t >> 6, l = t & 63;
  int cfg = tile >> 3, ks = tile & 7;
  int code = cfg * 16 + (l & 15);
  int k0 = (ks * 4 + (l >> 4)) * 8;
  const float4* src = (const float4*)(E + (size_t)code * DIM + k0);
  float4 a = src[0], b = src[1];
  uint4 o;
  o.x = pack2(a.x, a.y); o.y = pack2(a.z, a.w);
  o.z = pack2(b.x, b.y); o.w = pack2(b.z, b.w);
  Eb[t] = o;
}

// ---------------------------------------------------------------------------
// Single-pass swapped-operand MFMA + per-(row, 64-code-sub) min + flagging.
// 512 thr / 8 waves / block; block = 128 X-rows x all 8192 codes (64 chunks
// of 128). Wave: wcg = w&1 (64-code group, A-operand, 4 frags from LDS),
// wxg = w>>1 (32-xrow group, B-operand, bx[2][8] = 64 VGPR, loaded once).
// D rows = codes (lg*4+rg), cols = xrows (lane&15)  [m89 layout, swapped].
// Per chunk: in-register 16-code min per lane + shfl_xor(16,32) -> the
// 64-code sub-min per xrow -> submin[128 subs][128 rows] in LDS (64 KB).
// Epilogue: rowmin = min over subs; flag subs with submin <= rowmin + W
// (W = sqrt(a)*8e-6 + 1.8e-4, R7-proven g-form window) into global
// per-sub buckets (R6-proven consumer). No second MFMA pass, no cmin-to-HBM.
// ---------------------------------------------------------------------------
__global__ __launch_bounds__(512, 1) void vq_mfma_sub(
    const float* __restrict__ X, const uint4* __restrict__ Eb,
    const float* __restrict__ A, const float* __restrict__ C,
    unsigned* __restrict__ bcnt, int* __restrict__ buckets,
    unsigned* __restrict__ ovf) {
  __shared__ __align__(16) unsigned short es[128 * 256];   // 64 KB
  __shared__ float submin[128 * 128];                      // 64 KB

  const int tid  = threadIdx.x;        // 0..511
  const int lane = tid & 63, w = tid >> 6;
  const int lr   = lane & 15, lg = lane >> 4;
  const int wcg  = w & 1;              // 64-code group within chunk
  const int wxg  = w >> 1;             // 32-xrow group
  const int row0 = blockIdx.x * 128;

  // stage X tile into es as [128][256] bf16, R5-proven swizzle
  {
    const float4* Xg = (const float4*)(X + (size_t)row0 * DIM);
#pragma unroll
    for (int i = 0; i < 8; ++i) {
      int u = tid + i * 512;                     // 0..4095
      int r = u >> 5, kb = u & 31;
      float4 a = Xg[2 * u], b = Xg[2 * u + 1];
      uint4 o;
      o.x = pack2(a.x, a.y); o.y = pack2(a.z, a.w);
      o.z = pack2(b.x, b.y); o.w = pack2(b.z, b.w);
      *(uint4*)(es + (r * 256 + ((kb ^ (r & 31)) * 8))) = o;
    }
  }
  __syncthreads();

  // fill bx[2][8]: the wave's 32 X-rows, held in registers (64 VGPR)
  bf16x8 bx[2][8];
#pragma unroll
  for (int cf = 0; cf < 2; ++cf) {
    int row = wxg * 32 + cf * 16 + lr;
#pragma unroll
    for (int ks = 0; ks < 8; ++ks)
      bx[cf][ks] = *(const bf16x8*)(es + row * 256 + (((ks * 4 + lg) ^ (row & 31)) * 8));
  }
  __syncthreads();                     // bx filled; es free for E chunks

  // preload chunk 0 (register prefetch, R5/R7-proven) and stage it
  uint4 pf[8];
#pragma unroll
  for (int i = 0; i < 8; ++i) pf[i] = Eb[tid + i * 512];
#pragma unroll
  for (int i = 0; i < 8; ++i)
    *(uint4*)(es + (size_t)(tid + i * 512) * 8) = pf[i];
  __syncthreads();

  for (int c = 0; c < 64; ++c) {
    if (c + 1 < 64) {
#pragma unroll
      for (int i = 0; i < 8; ++i)
        pf[i] = Eb[(size_t)(c + 1) * 4096 + tid + i * 512];
    }

    // C values for this chunk: code = c*128 + wcg*64 + rf*16 + lg*4 + rg
    float Cv[16];
    {
      const int cbase = c * 128 + wcg * 64 + lg * 4;
#pragma unroll
      for (int rf = 0; rf < 4; ++rf)
#pragma unroll
        for (int rg = 0; rg < 4; ++rg)
          Cv[rf * 4 + rg] = C[cbase + rf * 16 + rg];
    }

    f32x4 acc[4][2];
#pragma unroll
    for (int rf = 0; rf < 4; ++rf)
#pragma unroll
      for (int cf = 0; cf < 2; ++cf)
        acc[rf][cf] = (f32x4){0.f, 0.f, 0.f, 0.f};

#pragma unroll
    for (int ks = 0; ks < 8; ++ks) {
      bf16x8 ev[4];
#pragma unroll
      for (int rf = 0; rf < 4; ++rf)
        ev[rf] = *(const bf16x8*)(es + (((wcg * 4 + rf) * 8 + ks) * 64 + lane) * 8);
#pragma unroll
      for (int rf = 0; rf < 4; ++rf) {
        acc[rf][0] = __builtin_amdgcn_mfma_f32_16x16x32_bf16(ev[rf], bx[0][ks], acc[rf][0], 0, 0, 0);
        acc[rf][1] = __builtin_amdgcn_mfma_f32_16x16x32_bf16(ev[rf], bx[1][ks], acc[rf][1], 0, 0, 0);
      }
    }

    // g = C - 2*b_hat; per-lane min over its 16 codes, then lanes lg merge
#pragma unroll
    for (int cf = 0; cf < 2; ++cf) {
      float m = fmaf(-2.0f, acc[0][cf][0], Cv[0]);
#pragma unroll
      for (int rf = 0; rf < 4; ++rf)
#pragma unroll
        for (int rg = 0; rg < 4; ++rg)
          if (rf | rg)
            m = fminf(m, fmaf(-2.0f, acc[rf][cf][rg], Cv[rf * 4 + rg]));
      m = fminf(m, __shfl_xor(m, 16));
      m = fminf(m, __shfl_xor(m, 32));
      if (lg == 0)
        submin[(c * 2 + wcg) * 128 + wxg * 32 + cf * 16 + lr] = m;
    }

    __syncthreads();                   // es reads of chunk c complete
    if (c + 1 < 64) {
#pragma unroll
      for (int i = 0; i < 8; ++i)
        *(uint4*)(es + (size_t)(tid + i * 512) * 8) = pf[i];
      __syncthreads();                 // chunk c+1 staged
    }
  }
  __syncthreads();                     // all submin writes visible

  // epilogue: per-row final min over 128 subs, window flag -> global buckets
  if (tid < 128) {
    int row = row0 + tid;
    float m = submin[tid];
    for (int s = 1; s < 128; ++s)
      m = fminf(m, submin[s * 128 + tid]);
    float thr = m + (sqrtf(A[row]) * 8e-6f + 1.8e-4f);
    for (int s = 0; s < 128; ++s) {
      if (submin[s * 128 + tid] <= thr) {
        unsigned p = atomicAdd(&bcnt[s], 1u);
        if (p < BCAP) buckets[s * BCAP + p] = row;
        else          ovf[row] = 1u;
      }
    }
  }
}

// ---------------------------------------------------------------------------
// Sparse exact (R6-proven, absmax 0.0): per (row, 64-code sub), one wave,
// lane <-> code; exact f32 ascending-fmaf chain; packed (d,j) atomicMin
// (d ~ 256 > 0 so float-bit order == float order; low word = first-index).
// ---------------------------------------------------------------------------
__global__ __launch_bounds__(256) void vq_exact(
    const float* __restrict__ X, const float* __restrict__ E,
    const float* __restrict__ A, const float* __restrict__ C,
    const unsigned* __restrict__ bcnt, const int* __restrict__ buckets,
    unsigned long long* __restrict__ best) {
  __shared__ float e_lds[64][260];     // 64 codes x 256 k, +4 pad
  __shared__ float xr[4][256];
  const int tid  = threadIdx.x;
  const int lane = tid & 63, w = tid >> 6;
  const int bk   = blockIdx.x >> 1, half = blockIdx.x & 1;

#pragma unroll
  for (int i = 0; i < 16; ++i) {       // stage E sub (exact f32 copy)
    int u = tid + i * 256;             // 0..4095
    int code = u >> 6, koff = (u & 63) * 4;
    float4 v = *(const float4*)(E + (size_t)(bk * 64 + code) * DIM + koff);
    *(float4*)(&e_lds[code][koff]) = v;
  }
  __syncthreads();

  int n = (int)bcnt[bk]; if (n > BCAP) n = BCAP;
  const int   j  = bk * 64 + lane;
  const float cj = C[j];

  for (int p = half * 4 + w; p < n; p += 8) {
    int row = buckets[bk * BCAP + p];
    *(float4*)(&xr[w][lane * 4]) = *(const float4*)(X + (size_t)row * DIM + lane * 4);
    asm volatile("s_waitcnt lgkmcnt(0)" ::: "memory");   // wave-level x visibility
    float a_r = A[row];
    float acc = 0.f;
#pragma unroll 4
    for (int kq = 0; kq < 64; ++kq) {
      float4 xv = *(const float4*)(&xr[w][kq * 4]);
      float4 ev = *(const float4*)(&e_lds[lane][kq * 4]);
      acc = fmaf(xv.x, ev.x, acc); acc = fmaf(xv.y, ev.y, acc);
      acc = fmaf(xv.z, ev.z, acc); acc = fmaf(xv.w, ev.w, acc);
    }
    float bd = (a_r - 2.0f * acc) + cj;
    int   bj = j;
    for (int mm = 1; mm < 64; mm <<= 1) {
      float od = __shfl_xor(bd, mm);
      int   oj = __shfl_xor(bj, mm);
      if (od < bd || (od == bd && oj < bj)) { bd = od; bj = oj; }
    }
    if (lane == 0) {
      unsigned long long pk = ((unsigned long long)__float_as_uint(bd) << 32) |
                              (unsigned)bj;
      atomicMin(&best[row], pk);
    }
  }
}

// unpack best -> idx/idxf; bucket-overflow rows get an exact full scan (R6)
__global__ __launch_bounds__(256) void vq_finish(
    const float* __restrict__ X, const float* __restrict__ E,
    const float* __restrict__ A, const float* __restrict__ C,
    const unsigned* __restrict__ ovf, const unsigned long long* __restrict__ best,
    int* __restrict__ idx_out, float* __restrict__ idxf_out) {
  int row  = blockIdx.x * 4 + (threadIdx.x >> 6);
  int lane = threadIdx.x & 63;
  if (!ovf[row]) {
    if (lane == 0) {
      int j = (int)(best[row] & 0xffffffffu);
      idx_out[row]  = j;
      idxf_out[row] = (float)j;
    }
    return;
  }
  const float a_r = A[row];
  const float4* X4 = (const float4*)(X + (size_t)row * DIM);
  float bd = INFINITY; int bj = 0x7fffffff;
  for (int j = lane; j < K_EMB; j += 64) {
    const float4* E4 = (const float4*)(E + (size_t)j * DIM);
    float acc = 0.f;
    for (int kb = 0; kb < 64; ++kb) {
      float4 xv = X4[kb], ev = E4[kb];
      acc = fmaf(xv.x, ev.x, acc); acc = fmaf(xv.y, ev.y, acc);
      acc = fmaf(xv.z, ev.z, acc); acc = fmaf(xv.w, ev.w, acc);
    }
    float d = (a_r - 2.0f * acc) + C[j];
    if (d < bd || (d == bd && j < bj)) { bd = d; bj = j; }
  }
  for (int m = 1; m < 64; m <<= 1) {
    float od = __shfl_xor(bd, m);
    int   oj = __shfl_xor(bj, m);
    if (od < bd || (od == bd && oj < bj)) { bd = od; bj = oj; }
  }
  if (lane == 0) { idx_out[row] = bj; idxf_out[row] = (float)bj; }
}

// ---------------------------------------------------------------------------
// Exact brute-force argmin (R2-proven) — ws-too-small fallback.
// ---------------------------------------------------------------------------
__global__ __launch_bounds__(256) void vq_argmin(const float* __restrict__ X,
                                                 const float* __restrict__ E,
                                                 const float* __restrict__ A,
                                                 const float* __restrict__ C,
                                                 int* __restrict__ idx_out,
                                                 float* __restrict__ idxf_out) {
  __shared__ float4 xs4[64 * 64];
  const int tid  = threadIdx.x;
  const int rl   = tid >> 2;
  const int cg   = tid & 3;
  const int row0 = blockIdx.x * 64;

  const float4* Xg = (const float4*)(X + (size_t)row0 * DIM);
  for (int it = 0; it < 16; ++it) {
    int f4 = tid + it * 256;
    float4 v = Xg[f4];
    int r = f4 >> 6, kb = f4 & 63;
    xs4[r * 64 + (kb ^ (r & 7))] = v;
  }
  __syncthreads();

  const float a_r = A[row0 + rl];
  const int   swq = rl & 7;
  const float4* xrow = xs4 + rl * 64;

  float bd = INFINITY;
  int   bj = 0x7fffffff;

  for (int tile = 0; tile < K_EMB; tile += 16) {
    const int j0 = tile + cg * 4;
    const float4* e0 = (const float4*)(E + (size_t)(j0 + 0) * DIM);
    const float4* e1 = (const float4*)(E + (size_t)(j0 + 1) * DIM);
    const float4* e2 = (const float4*)(E + (size_t)(j0 + 2) * DIM);
    const float4* e3 = (const float4*)(E + (size_t)(j0 + 3) * DIM);
    float acc0 = 0.f, acc1 = 0.f, acc2 = 0.f, acc3 = 0.f;
#pragma unroll 4
    for (int kb = 0; kb < 64; ++kb) {
      const float4 xv = xrow[kb ^ swq];
      const float4 q0 = e0[kb], q1 = e1[kb], q2 = e2[kb], q3 = e3[kb];
      acc0 = fmaf(xv.x, q0.x, acc0); acc0 = fmaf(xv.y, q0.y, acc0);
      acc0 = fmaf(xv.z, q0.z, acc0); acc0 = fmaf(xv.w, q0.w, acc0);
      acc1 = fmaf(xv.x, q1.x, acc1); acc1 = fmaf(xv.y, q1.y, acc1);
      acc1 = fmaf(xv.z, q1.z, acc1); acc1 = fmaf(xv.w, q1.w, acc1);
      acc2 = fmaf(xv.x, q2.x, acc2); acc2 = fmaf(xv.y, q2.y, acc2);
      acc2 = fmaf(xv.z, q2.z, acc2); acc2 = fmaf(xv.w, q2.w, acc2);
      acc3 = fmaf(xv.x, q3.x, acc3); acc3 = fmaf(xv.y, q3.y, acc3);
      acc3 = fmaf(xv.z, q3.z, acc3); acc3 = fmaf(xv.w, q3.w, acc3);
    }
    const float d0 = (a_r - 2.0f * acc0) + C[j0 + 0];
    const float d1 = (a_r - 2.0f * acc1) + C[j0 + 1];
    const float d2 = (a_r - 2.0f * acc2) + C[j0 + 2];
    const float d3 = (a_r - 2.0f * acc3) + C[j0 + 3];
    if (d0 < bd) { bd = d0; bj = j0 + 0; }
    if (d1 < bd) { bd = d1; bj = j0 + 1; }
    if (d2 < bd) { bd = d2; bj = j0 + 2; }
    if (d3 < bd) { bd = d3; bj = j0 + 3; }
  }
  for (int m = 1; m < 4; m <<= 1) {
    float od = __shfl_xor(bd, m);
    int   oj = __shfl_xor(bj, m);
    if (od < bd || (od == bd && oj < bj)) { bd = od; bj = oj; }
  }
  if (cg == 0) {
    int row = row0 + rl;
    idx_out[row]  = bj;
    idxf_out[row] = (float)bj;
  }
}

// ---------------------------------------------------------------------------
// quantized_st + loss partials / hist / scalars (R2..R7 proven)
// ---------------------------------------------------------------------------
__global__ __launch_bounds__(256) void vq_quant(const float* __restrict__ X,
                                                const float* __restrict__ E,
                                                const int* __restrict__ idx,
                                                float* __restrict__ out_qst,
                                                double* __restrict__ partials) {
  int gid  = blockIdx.x * 256 + threadIdx.x;
  int base = gid * 4;
  int row  = base >> 8;
  int k    = base & 255;
  int j    = idx[row];
  const float4 xv = *(const float4*)(X + (size_t)base);
  const float4 ev = *(const float4*)(E + (size_t)j * DIM + k);
  float4 o;
  float d0 = ev.x - xv.x, d1 = ev.y - xv.y, d2 = ev.z - xv.z, d3 = ev.w - xv.w;
  o.x = xv.x + d0; o.y = xv.y + d1; o.z = xv.z + d2; o.w = xv.w + d3;
  double s = (double)d0 * d0 + (double)d1 * d1 + (double)d2 * d2 + (double)d3 * d3;
  *(float4*)(out_qst + (size_t)base) = o;

  for (int m = 32; m; m >>= 1) s += __shfl_xor(s, m);
  __shared__ double wsum[4];
  int lane = threadIdx.x & 63, w = threadIdx.x >> 6;
  if (lane == 0) wsum[w] = s;
  __syncthreads();
  if (threadIdx.x == 0)
    partials[blockIdx.x] = (wsum[0] + wsum[1]) + (wsum[2] + wsum[3]);
}

__global__ void vq_zero(unsigned* counts) {
  int i = blockIdx.x * 256 + threadIdx.x;
  if (i < K_EMB) counts[i] = 0u;
}

__global__ void vq_hist(const int* __restrict__ idx, unsigned* __restrict__ counts) {
  int i = blockIdx.x * 256 + threadIdx.x;
  if (i < N_ROWS) atomicAdd(&counts[idx[i]], 1u);
}

__global__ __launch_bounds__(256) void vq_scalars(const double* __restrict__ partials,
                                                  const unsigned* __restrict__ counts,
                                                  float* __restrict__ out_loss,
                                                  float* __restrict__ out_perp) {
  __shared__ double red[256];
  int t = threadIdx.x;
  double s = 0.0;
  for (int i = t; i < 8192; i += 256) s += partials[i];
  red[t] = s;
  __syncthreads();
  for (int o = 128; o; o >>= 1) { if (t < o) red[t] += red[t + o]; __syncthreads(); }
  double mse = red[0] / (double)((size_t)N_ROWS * DIM);
  __syncthreads();

  double p = 0.0;
  for (int i = t; i < K_EMB; i += 256) {
    double pr = (double)counts[i] / (double)N_ROWS;
    p += pr * log(pr + 1e-10);
  }
  red[t] = p;
  __syncthreads();
  for (int o = 128; o; o >>= 1) { if (t < o) red[t] += red[t + o]; __syncthreads(); }
  if (t == 0) {
    float m = (float)mse;
    out_loss[0] = m + 0.25f * m;
    out_perp[0] = (float)exp(-red[0]);
  }
}

extern "C" void kernel_launch(void* const* d_in, const int* in_sizes, int n_in,
                              void* d_out, int out_size, void* d_ws, size_t ws_size,
                              hipStream_t stream) {
  const float* X = (const float*)d_in[0];   // [32768, 256]
  const float* E = (const float*)d_in[1];   // [8192, 256]
  float* out  = (float*)d_out;
  float* qst  = out;
  float* loss = out + 8388608;
  float* perp = out + 8388609;
  float* idxf = out + 8388610;

  // ws layout (bytes):
  //       0: A        f32[32768]
  //  131072: C        f32[8192]
  //  163840: idx      i32[32768]
  //  294912: hist     u32[8192]
  //  327680: partials f64[8192]
  //  393216: best     u64[32768]     (262144)
  //  655360: ovf      u32[32768]     (131072)
  //  786432: bcnt     u32[128]       (512)
  //  786944: buckets  i32[128*4096]  (2097152)
  // 2884096: Eb       bf16[8192*256] (4194304)  -> total 7078400
  float*    A        = (float*)d_ws;
  float*    C        = (float*)((char*)d_ws + 131072);
  int*      idx      = (int*)((char*)d_ws + 163840);
  unsigned* hist     = (unsigned*)((char*)d_ws + 294912);
  double*   partials = (double*)((char*)d_ws + 327680);

  vq_sumsq <<<256, 256, 0, stream>>>(X, A, N_ROWS);
  vq_sumsq <<<64,  256, 0, stream>>>(E, C, K_EMB);

  if (ws_size >= 7078400) {
    unsigned long long* best = (unsigned long long*)((char*)d_ws + 393216);
    unsigned* ovf     = (unsigned*)((char*)d_ws + 655360);
    unsigned* bcnt    = (unsigned*)((char*)d_ws + 786432);
    int*      buckets = (int*)((char*)d_ws + 786944);
    uint4*    Eb      = (uint4*)((char*)d_ws + 2884096);

    vq_init     <<<128,  256, 0, stream>>>(hist, bcnt, ovf, best);
    vq_cvt_frag <<<1024, 256, 0, stream>>>(E, Eb);
    vq_mfma_sub <<<256,  512, 0, stream>>>(X, Eb, A, C, bcnt, buckets, ovf);
    vq_exact    <<<256,  256, 0, stream>>>(X, E, A, C, bcnt, buckets, best);
    vq_finish   <<<8192, 256, 0, stream>>>(X, E, A, C, ovf, best, idx, idxf);
  } else {
    vq_zero   <<<32,  256, 0, stream>>>(hist);
    vq_argmin <<<512, 256, 0, stream>>>(X, E, A, C, idx, idxf);
  }

  vq_quant  <<<8192, 256, 0, stream>>>(X, E, idx, qst, partials);
  vq_hist   <<<128,  256, 0, stream>>>(idx, hist);
  vq_scalars<<<1,    256, 0, stream>>>(partials, hist, loss, perp);
}

// Round 9
// 664.026 us; speedup vs baseline: 1.4247x; 1.4247x over previous
//
#include <hip/hip_runtime.h>
#include <math.h>

// No automatic FMA contraction anywhere: numpy-emulation arithmetic
// (square-then-add, sub-then-add) must round exactly like the reference.
// Explicit fmaf() stays fused regardless.
#pragma clang fp contract(off)

#define N_ROWS 32768
#define DIM    256
#define K_EMB  8192
#define BCAP   4096

// submin u16 fixed-point: q = floor((g + 0.125) * 2^18), dequant exact in f32
#define SM_SCALE 262144.0f
#define SM_INV   3.814697265625e-06f
#define SM_BIAS  0.125f

typedef float  f32x4  __attribute__((ext_vector_type(4)));
typedef short  bf16x8 __attribute__((ext_vector_type(8)));

__device__ __forceinline__ unsigned bf_rne(float f) {
  unsigned u = __float_as_uint(f);
  return (u + 0x7fffu + ((u >> 16) & 1u)) >> 16;   // RNE f32->bf16 (no NaN in data)
}
__device__ __forceinline__ unsigned pack2(float lo, float hi) {
  return bf_rne(lo) | (bf_rne(hi) << 16);
}

// ---------------------------------------------------------------------------
// numpy pairwise_sum emulation (exact order): R2..R8 proven, absmax 0.0.
// ---------------------------------------------------------------------------
__device__ __forceinline__ float np_pw128_sumsq(const float* __restrict__ a) {
  float4 v0 = *(const float4*)(a);
  float4 v1 = *(const float4*)(a + 4);
  float r0 = v0.x*v0.x, r1 = v0.y*v0.y, r2 = v0.z*v0.z, r3 = v0.w*v0.w;
  float r4 = v1.x*v1.x, r5 = v1.y*v1.y, r6 = v1.z*v1.z, r7 = v1.w*v1.w;
  for (int i = 8; i < 128; i += 8) {
    float4 w0 = *(const float4*)(a + i);
    float4 w1 = *(const float4*)(a + i + 4);
    r0 += w0.x*w0.x; r1 += w0.y*w0.y; r2 += w0.z*w0.z; r3 += w0.w*w0.w;
    r4 += w1.x*w1.x; r5 += w1.y*w1.y; r6 += w1.z*w1.z; r7 += w1.w*w1.w;
  }
  return ((r0+r1)+(r2+r3))+((r4+r5)+(r6+r7));
}

__global__ __launch_bounds__(256) void vq_sumsq(const float* __restrict__ src,
                                                float* __restrict__ dst, int nrows) {
  int gid  = blockIdx.x * 256 + threadIdx.x;
  int row  = gid >> 1, half = gid & 1;
  if (row >= nrows) return;
  float s = np_pw128_sumsq(src + (size_t)row * DIM + half * 128);
  float o = __shfl_xor(s, 1);
  if (half == 0) dst[row] = s + o;     // fl(s0 + s1), numpy order
}

// init small arrays (ws poisoned 0xAA by harness) — R6/R8-proven
__global__ __launch_bounds__(256) void vq_init(unsigned* __restrict__ hist,
                                               unsigned* __restrict__ bcnt,
                                               unsigned* __restrict__ ovf,
                                               unsigned long long* __restrict__ best) {
  int i = blockIdx.x * 256 + threadIdx.x;      // grid 128*256 = 32768
  ovf[i]  = 0u;
  best[i] = ~0ull;
  if (i < K_EMB) hist[i] = 0u;
  if (i < 128)   bcnt[i] = 0u;
}

// E f32 -> bf16 in MFMA-fragment-tile order (R6..R8-proven).
__global__ __launch_bounds__(256) void vq_cvt_frag(const float* __restrict__ E,
                                                   uint4* __restrict__ Eb) {
  int t = blockIdx.x * 256 + threadIdx.x;      // 0..262143 (tile*64 + lane)
  int tile = t >> 6, l = t & 63;
  int cfg = tile >> 3, ks = tile & 7;
  int code = cfg * 16 + (l & 15);
  int k0 = (ks * 4 + (l >> 4)) * 8;
  const float4* src = (const float4*)(E + (size_t)code * DIM + k0);
  float4 a = src[0], b = src[1];
  uint4 o;
  o.x = pack2(a.x, a.y); o.y = pack2(a.z, a.w);
  o.z = pack2(b.x, b.y); o.w = pack2(b.z, b.w);
  Eb[t] = o;
}

// ---------------------------------------------------------------------------
// Single-pass swapped-operand MFMA + per-(row, 64-code-sub) min + flagging.
// R8 structure with two fixes:
//  (1) amdgpu_waves_per_eu(2,2): pins the register budget to 512/2 = 256
//      VGPR/wave (occupancy is LDS-capped at 2 waves/SIMD anyway). R7/R8's
//      ~100-reg scratch spill (WRITE_SIZE 450-474 MB) should vanish.
//  (2) true double-buffered es + ONE barrier per chunk:
//      LOADC(c+1)->pf; MFMA on es[cur]; WRITEC(c+1)->es[cur^1]; barrier.
//      Writing the other buffer while reading the current one is race-free.
//  submin stored as u16 fixed-point (monotone floor quant, exact dequant,
//  +4e-6 W slack keeps the window a superset) so LDS = 128K + 32K = 160 KiB.
// ---------------------------------------------------------------------------
__global__ __launch_bounds__(512)
__attribute__((amdgpu_waves_per_eu(2, 2)))
void vq_mfma_sub2(
    const float* __restrict__ X, const uint4* __restrict__ Eb,
    const float* __restrict__ A, const float* __restrict__ C,
    unsigned* __restrict__ bcnt, int* __restrict__ buckets,
    unsigned* __restrict__ ovf) {
  __shared__ __align__(16) unsigned short es[2][128 * 256];  // 2 x 64 KB
  __shared__ unsigned short submin_q[128 * 128];             // 32 KB

  const int tid  = threadIdx.x;        // 0..511
  const int lane = tid & 63, w = tid >> 6;
  const int lr   = lane & 15, lg = lane >> 4;
  const int wcg  = w & 1;              // 64-code group within chunk
  const int wxg  = w >> 1;             // 32-xrow group
  const int row0 = blockIdx.x * 128;

  // stage X tile into es[1] as [128][256] bf16, R5-proven swizzle
  {
    const float4* Xg = (const float4*)(X + (size_t)row0 * DIM);
#pragma unroll
    for (int i = 0; i < 8; ++i) {
      int u = tid + i * 512;                     // 0..4095
      int r = u >> 5, kb = u & 31;
      float4 a = Xg[2 * u], b = Xg[2 * u + 1];
      uint4 o;
      o.x = pack2(a.x, a.y); o.y = pack2(a.z, a.w);
      o.z = pack2(b.x, b.y); o.w = pack2(b.z, b.w);
      *(uint4*)(&es[1][0] + (r * 256 + ((kb ^ (r & 31)) * 8))) = o;
    }
  }
  __syncthreads();

  // prefetch chunk 0 while reading bx (the wave's 32 X-rows, 64 VGPR)
  uint4 pf[8];
#pragma unroll
  for (int i = 0; i < 8; ++i) pf[i] = Eb[tid + i * 512];

  bf16x8 bx[2][8];
#pragma unroll
  for (int cf = 0; cf < 2; ++cf) {
    int row = wxg * 32 + cf * 16 + lr;
#pragma unroll
    for (int ks = 0; ks < 8; ++ks)
      bx[cf][ks] = *(const bf16x8*)(&es[1][0] + row * 256 + (((ks * 4 + lg) ^ (row & 31)) * 8));
  }

  // stage chunk 0 into es[0] (es[0] untouched so far -> no barrier needed)
#pragma unroll
  for (int i = 0; i < 8; ++i)
    *(uint4*)(&es[0][0] + (size_t)(tid + i * 512) * 8) = pf[i];
  __syncthreads();                     // bx reads + chunk-0 writes complete

  for (int c = 0; c < 64; ++c) {
    const int cur = c & 1;
    if (c + 1 < 64) {
#pragma unroll
      for (int i = 0; i < 8; ++i)
        pf[i] = Eb[(size_t)(c + 1) * 4096 + tid + i * 512];
    }

    // C values: code = c*128 + wcg*64 + rf*16 + lg*4 + rg
    float Cv[16];
    {
      const int cbase = c * 128 + wcg * 64 + lg * 4;
#pragma unroll
      for (int rf = 0; rf < 4; ++rf)
#pragma unroll
        for (int rg = 0; rg < 4; ++rg)
          Cv[rf * 4 + rg] = C[cbase + rf * 16 + rg];
    }

    f32x4 acc[4][2];
#pragma unroll
    for (int rf = 0; rf < 4; ++rf)
#pragma unroll
      for (int cf = 0; cf < 2; ++cf)
        acc[rf][cf] = (f32x4){0.f, 0.f, 0.f, 0.f};

    const unsigned short* eb = &es[cur][0];
#pragma unroll
    for (int ks = 0; ks < 8; ++ks) {
      bf16x8 ev[4];
#pragma unroll
      for (int rf = 0; rf < 4; ++rf)
        ev[rf] = *(const bf16x8*)(eb + (((wcg * 4 + rf) * 8 + ks) * 64 + lane) * 8);
#pragma unroll
      for (int rf = 0; rf < 4; ++rf) {
        acc[rf][0] = __builtin_amdgcn_mfma_f32_16x16x32_bf16(ev[rf], bx[0][ks], acc[rf][0], 0, 0, 0);
        acc[rf][1] = __builtin_amdgcn_mfma_f32_16x16x32_bf16(ev[rf], bx[1][ks], acc[rf][1], 0, 0, 0);
      }
    }

    // g = C - 2*b_hat; per-lane min over 16 codes; lanes lg merge -> 64-code
    // sub-min; floor-quantize to u16 (monotone) and store (race-free slots)
#pragma unroll
    for (int cf = 0; cf < 2; ++cf) {
      float m = fmaf(-2.0f, acc[0][cf][0], Cv[0]);
#pragma unroll
      for (int rf = 0; rf < 4; ++rf)
#pragma unroll
        for (int rg = 0; rg < 4; ++rg)
          if (rf | rg)
            m = fminf(m, fmaf(-2.0f, acc[rf][cf][rg], Cv[rf * 4 + rg]));
      m = fminf(m, __shfl_xor(m, 16));
      m = fminf(m, __shfl_xor(m, 32));
      if (lg == 0) {
        int qi = (int)((m + SM_BIAS) * SM_SCALE);
        qi = qi < 0 ? 0 : (qi > 65535 ? 65535 : qi);
        submin_q[(c * 2 + wcg) * 128 + wxg * 32 + cf * 16 + lr] = (unsigned short)qi;
      }
    }

    if (c + 1 < 64) {                  // write NEXT chunk into the other buffer
      unsigned short* ew = &es[cur ^ 1][0];
#pragma unroll
      for (int i = 0; i < 8; ++i)
        *(uint4*)(ew + (size_t)(tid + i * 512) * 8) = pf[i];
    }
    __syncthreads();                   // single barrier: cur reads + cur^1 writes
  }

  // epilogue: per-row final min over 128 subs, window flag -> global buckets
  if (tid < 128) {
    int row = row0 + tid;
    int mq = 65535;
    for (int s = 0; s < 128; ++s) {
      int q = submin_q[s * 128 + tid];
      mq = q < mq ? q : mq;
    }
    float gmin = (float)mq * SM_INV - SM_BIAS;
    float thr  = gmin + (sqrtf(A[row]) * 8e-6f + 1.84e-4f);  // +4e-6 quant slack
    for (int s = 0; s < 128; ++s) {
      float gs = (float)submin_q[s * 128 + tid] * SM_INV - SM_BIAS;
      if (gs <= thr) {
        unsigned p = atomicAdd(&bcnt[s], 1u);
        if (p < BCAP) buckets[s * BCAP + p] = row;
        else          ovf[row] = 1u;
      }
    }
  }
}

// ---------------------------------------------------------------------------
// Sparse exact (R6/R8-proven, absmax 0.0): per (row, 64-code sub), one wave,
// lane <-> code; exact f32 ascending-fmaf chain; packed (d,j) atomicMin.
// Grid 512: 4 blocks per sub (quarter-split) for more parallelism.
// ---------------------------------------------------------------------------
__global__ __launch_bounds__(256) void vq_exact(
    const float* __restrict__ X, const float* __restrict__ E,
    const float* __restrict__ A, const float* __restrict__ C,
    const unsigned* __restrict__ bcnt, const int* __restrict__ buckets,
    unsigned long long* __restrict__ best) {
  __shared__ float e_lds[64][260];     // 64 codes x 256 k, +4 pad
  __shared__ float xr[4][256];
  const int tid  = threadIdx.x;
  const int lane = tid & 63, w = tid >> 6;
  const int bk   = blockIdx.x >> 2, q4 = blockIdx.x & 3;

#pragma unroll
  for (int i = 0; i < 16; ++i) {       // stage E sub (exact f32 copy)
    int u = tid + i * 256;             // 0..4095
    int code = u >> 6, koff = (u & 63) * 4;
    float4 v = *(const float4*)(E + (size_t)(bk * 64 + code) * DIM + koff);
    *(float4*)(&e_lds[code][koff]) = v;
  }
  __syncthreads();

  int n = (int)bcnt[bk]; if (n > BCAP) n = BCAP;
  const int   j  = bk * 64 + lane;
  const float cj = C[j];

  for (int p = q4 * 4 + w; p < n; p += 16) {
    int row = buckets[bk * BCAP + p];
    *(float4*)(&xr[w][lane * 4]) = *(const float4*)(X + (size_t)row * DIM + lane * 4);
    asm volatile("s_waitcnt lgkmcnt(0)" ::: "memory");   // wave-level x visibility
    float a_r = A[row];
    float acc = 0.f;
#pragma unroll 4
    for (int kq = 0; kq < 64; ++kq) {
      float4 xv = *(const float4*)(&xr[w][kq * 4]);
      float4 ev = *(const float4*)(&e_lds[lane][kq * 4]);
      acc = fmaf(xv.x, ev.x, acc); acc = fmaf(xv.y, ev.y, acc);
      acc = fmaf(xv.z, ev.z, acc); acc = fmaf(xv.w, ev.w, acc);
    }
    float bd = (a_r - 2.0f * acc) + cj;
    int   bj = j;
    for (int mm = 1; mm < 64; mm <<= 1) {
      float od = __shfl_xor(bd, mm);
      int   oj = __shfl_xor(bj, mm);
      if (od < bd || (od == bd && oj < bj)) { bd = od; bj = oj; }
    }
    if (lane == 0) {
      unsigned long long pk = ((unsigned long long)__float_as_uint(bd) << 32) |
                              (unsigned)bj;
      atomicMin(&best[row], pk);
    }
  }
}

// unpack best -> idx/idxf; bucket-overflow rows get an exact full scan (R6)
__global__ __launch_bounds__(256) void vq_finish(
    const float* __restrict__ X, const float* __restrict__ E,
    const float* __restrict__ A, const float* __restrict__ C,
    const unsigned* __restrict__ ovf, const unsigned long long* __restrict__ best,
    int* __restrict__ idx_out, float* __restrict__ idxf_out) {
  int row  = blockIdx.x * 4 + (threadIdx.x >> 6);
  int lane = threadIdx.x & 63;
  if (!ovf[row]) {
    if (lane == 0) {
      int j = (int)(best[row] & 0xffffffffu);
      idx_out[row]  = j;
      idxf_out[row] = (float)j;
    }
    return;
  }
  const float a_r = A[row];
  const float4* X4 = (const float4*)(X + (size_t)row * DIM);
  float bd = INFINITY; int bj = 0x7fffffff;
  for (int j = lane; j < K_EMB; j += 64) {
    const float4* E4 = (const float4*)(E + (size_t)j * DIM);
    float acc = 0.f;
    for (int kb = 0; kb < 64; ++kb) {
      float4 xv = X4[kb], ev = E4[kb];
      acc = fmaf(xv.x, ev.x, acc); acc = fmaf(xv.y, ev.y, acc);
      acc = fmaf(xv.z, ev.z, acc); acc = fmaf(xv.w, ev.w, acc);
    }
    float d = (a_r - 2.0f * acc) + C[j];
    if (d < bd || (d == bd && j < bj)) { bd = d; bj = j; }
  }
  for (int m = 1; m < 64; m <<= 1) {
    float od = __shfl_xor(bd, m);
    int   oj = __shfl_xor(bj, m);
    if (od < bd || (od == bd && oj < bj)) { bd = od; bj = oj; }
  }
  if (lane == 0) { idx_out[row] = bj; idxf_out[row] = (float)bj; }
}

// ---------------------------------------------------------------------------
// Exact brute-force argmin (R2-proven) — ws-too-small fallback.
// ---------------------------------------------------------------------------
__global__ __launch_bounds__(256) void vq_argmin(const float* __restrict__ X,
                                                 const float* __restrict__ E,
                                                 const float* __restrict__ A,
                                                 const float* __restrict__ C,
                                                 int* __restrict__ idx_out,
                                                 float* __restrict__ idxf_out) {
  __shared__ float4 xs4[64 * 64];
  const int tid  = threadIdx.x;
  const int rl   = tid >> 2;
  const int cg   = tid & 3;
  const int row0 = blockIdx.x * 64;

  const float4* Xg = (const float4*)(X + (size_t)row0 * DIM);
  for (int it = 0; it < 16; ++it) {
    int f4 = tid + it * 256;
    float4 v = Xg[f4];
    int r = f4 >> 6, kb = f4 & 63;
    xs4[r * 64 + (kb ^ (r & 7))] = v;
  }
  __syncthreads();

  const float a_r = A[row0 + rl];
  const int   swq = rl & 7;
  const float4* xrow = xs4 + rl * 64;

  float bd = INFINITY;
  int   bj = 0x7fffffff;

  for (int tile = 0; tile < K_EMB; tile += 16) {
    const int j0 = tile + cg * 4;
    const float4* e0 = (const float4*)(E + (size_t)(j0 + 0) * DIM);
    const float4* e1 = (const float4*)(E + (size_t)(j0 + 1) * DIM);
    const float4* e2 = (const float4*)(E + (size_t)(j0 + 2) * DIM);
    const float4* e3 = (const float4*)(E + (size_t)(j0 + 3) * DIM);
    float acc0 = 0.f, acc1 = 0.f, acc2 = 0.f, acc3 = 0.f;
#pragma unroll 4
    for (int kb = 0; kb < 64; ++kb) {
      const float4 xv = xrow[kb ^ swq];
      const float4 q0 = e0[kb], q1 = e1[kb], q2 = e2[kb], q3 = e3[kb];
      acc0 = fmaf(xv.x, q0.x, acc0); acc0 = fmaf(xv.y, q0.y, acc0);
      acc0 = fmaf(xv.z, q0.z, acc0); acc0 = fmaf(xv.w, q0.w, acc0);
      acc1 = fmaf(xv.x, q1.x, acc1); acc1 = fmaf(xv.y, q1.y, acc1);
      acc1 = fmaf(xv.z, q1.z, acc1); acc1 = fmaf(xv.w, q1.w, acc1);
      acc2 = fmaf(xv.x, q2.x, acc2); acc2 = fmaf(xv.y, q2.y, acc2);
      acc2 = fmaf(xv.z, q2.z, acc2); acc2 = fmaf(xv.w, q2.w, acc2);
      acc3 = fmaf(xv.x, q3.x, acc3); acc3 = fmaf(xv.y, q3.y, acc3);
      acc3 = fmaf(xv.z, q3.z, acc3); acc3 = fmaf(xv.w, q3.w, acc3);
    }
    const float d0 = (a_r - 2.0f * acc0) + C[j0 + 0];
    const float d1 = (a_r - 2.0f * acc1) + C[j0 + 1];
    const float d2 = (a_r - 2.0f * acc2) + C[j0 + 2];
    const float d3 = (a_r - 2.0f * acc3) + C[j0 + 3];
    if (d0 < bd) { bd = d0; bj = j0 + 0; }
    if (d1 < bd) { bd = d1; bj = j0 + 1; }
    if (d2 < bd) { bd = d2; bj = j0 + 2; }
    if (d3 < bd) { bd = d3; bj = j0 + 3; }
  }
  for (int m = 1; m < 4; m <<= 1) {
    float od = __shfl_xor(bd, m);
    int   oj = __shfl_xor(bj, m);
    if (od < bd || (od == bd && oj < bj)) { bd = od; bj = oj; }
  }
  if (cg == 0) {
    int row = row0 + rl;
    idx_out[row]  = bj;
    idxf_out[row] = (float)bj;
  }
}

// ---------------------------------------------------------------------------
// quantized_st + loss partials / hist / scalars (R2..R8 proven)
// ---------------------------------------------------------------------------
__global__ __launch_bounds__(256) void vq_quant(const float* __restrict__ X,
                                                const float* __restrict__ E,
                                                const int* __restrict__ idx,
                                                float* __restrict__ out_qst,
                                                double* __restrict__ partials) {
  int gid  = blockIdx.x * 256 + threadIdx.x;
  int base = gid * 4;
  int row  = base >> 8;
  int k    = base & 255;
  int j    = idx[row];
  const float4 xv = *(const float4*)(X + (size_t)base);
  const float4 ev = *(const float4*)(E + (size_t)j * DIM + k);
  float4 o;
  float d0 = ev.x - xv.x, d1 = ev.y - xv.y, d2 = ev.z - xv.z, d3 = ev.w - xv.w;
  o.x = xv.x + d0; o.y = xv.y + d1; o.z = xv.z + d2; o.w = xv.w + d3;
  double s = (double)d0 * d0 + (double)d1 * d1 + (double)d2 * d2 + (double)d3 * d3;
  *(float4*)(out_qst + (size_t)base) = o;

  for (int m = 32; m; m >>= 1) s += __shfl_xor(s, m);
  __shared__ double wsum[4];
  int lane = threadIdx.x & 63, w = threadIdx.x >> 6;
  if (lane == 0) wsum[w] = s;
  __syncthreads();
  if (threadIdx.x == 0)
    partials[blockIdx.x] = (wsum[0] + wsum[1]) + (wsum[2] + wsum[3]);
}

__global__ void vq_zero(unsigned* counts) {
  int i = blockIdx.x * 256 + threadIdx.x;
  if (i < K_EMB) counts[i] = 0u;
}

__global__ void vq_hist(const int* __restrict__ idx, unsigned* __restrict__ counts) {
  int i = blockIdx.x * 256 + threadIdx.x;
  if (i < N_ROWS) atomicAdd(&counts[idx[i]], 1u);
}

__global__ __launch_bounds__(256) void vq_scalars(const double* __restrict__ partials,
                                                  const unsigned* __restrict__ counts,
                                                  float* __restrict__ out_loss,
                                                  float* __restrict__ out_perp) {
  __shared__ double red[256];
  int t = threadIdx.x;
  double s = 0.0;
  for (int i = t; i < 8192; i += 256) s += partials[i];
  red[t] = s;
  __syncthreads();
  for (int o = 128; o; o >>= 1) { if (t < o) red[t] += red[t + o]; __syncthreads(); }
  double mse = red[0] / (double)((size_t)N_ROWS * DIM);
  __syncthreads();

  double p = 0.0;
  for (int i = t; i < K_EMB; i += 256) {
    double pr = (double)counts[i] / (double)N_ROWS;
    p += pr * log(pr + 1e-10);
  }
  red[t] = p;
  __syncthreads();
  for (int o = 128; o; o >>= 1) { if (t < o) red[t] += red[t + o]; __syncthreads(); }
  if (t == 0) {
    float m = (float)mse;
    out_loss[0] = m + 0.25f * m;
    out_perp[0] = (float)exp(-red[0]);
  }
}

extern "C" void kernel_launch(void* const* d_in, const int* in_sizes, int n_in,
                              void* d_out, int out_size, void* d_ws, size_t ws_size,
                              hipStream_t stream) {
  const float* X = (const float*)d_in[0];   // [32768, 256]
  const float* E = (const float*)d_in[1];   // [8192, 256]
  float* out  = (float*)d_out;
  float* qst  = out;
  float* loss = out + 8388608;
  float* perp = out + 8388609;
  float* idxf = out + 8388610;

  // ws layout (bytes) — identical to R8:
  //       0: A        f32[32768]
  //  131072: C        f32[8192]
  //  163840: idx      i32[32768]
  //  294912: hist     u32[8192]
  //  327680: partials f64[8192]
  //  393216: best     u64[32768]     (262144)
  //  655360: ovf      u32[32768]     (131072)
  //  786432: bcnt     u32[128]       (512)
  //  786944: buckets  i32[128*4096]  (2097152)
  // 2884096: Eb       bf16[8192*256] (4194304)  -> total 7078400
  float*    A        = (float*)d_ws;
  float*    C        = (float*)((char*)d_ws + 131072);
  int*      idx      = (int*)((char*)d_ws + 163840);
  unsigned* hist     = (unsigned*)((char*)d_ws + 294912);
  double*   partials = (double*)((char*)d_ws + 327680);

  vq_sumsq <<<256, 256, 0, stream>>>(X, A, N_ROWS);
  vq_sumsq <<<64,  256, 0, stream>>>(E, C, K_EMB);

  if (ws_size >= 7078400) {
    unsigned long long* best = (unsigned long long*)((char*)d_ws + 393216);
    unsigned* ovf     = (unsigned*)((char*)d_ws + 655360);
    unsigned* bcnt    = (unsigned*)((char*)d_ws + 786432);
    int*      buckets = (int*)((char*)d_ws + 786944);
    uint4*    Eb      = (uint4*)((char*)d_ws + 2884096);

    vq_init      <<<128,  256, 0, stream>>>(hist, bcnt, ovf, best);
    vq_cvt_frag  <<<1024, 256, 0, stream>>>(E, Eb);
    vq_mfma_sub2 <<<256,  512, 0, stream>>>(X, Eb, A, C, bcnt, buckets, ovf);
    vq_exact     <<<512,  256, 0, stream>>>(X, E, A, C, bcnt, buckets, best);
    vq_finish    <<<8192, 256, 0, stream>>>(X, E, A, C, ovf, best, idx, idxf);
  } else {
    vq_zero   <<<32,  256, 0, stream>>>(hist);
    vq_argmin <<<512, 256, 0, stream>>>(X, E, A, C, idx, idxf);
  }

  vq_quant  <<<8192, 256, 0, stream>>>(X, E, idx, qst, partials);
  vq_hist   <<<128,  256, 0, stream>>>(idx, hist);
  vq_scalars<<<1,    256, 0, stream>>>(partials, hist, loss, perp);
}